// Round 1
// baseline (1702.308 us; speedup 1.0000x reference)
//
#include <hip/hip_runtime.h>

#define FEAT 3
#define HID  20
#define NB   1024
#define TT   4096

__device__ __forceinline__ float fast_rcp(float x) { return __builtin_amdgcn_rcpf(x); }

// ---------------------------------------------------------------------------
// Kernel 1: LSTM scan. thread = (local batch lb in 0..3, gate row r in 0..79)
// block = 320 threads (5 waves) = 4 batches; grid = 256 blocks = 1 block/CU.
// Gate rows in torch order: r = gt*20 + j, gt: 0=i 1=f 2=g 3=o.
// ---------------------------------------------------------------------------
__global__ __launch_bounds__(320) void lstm_scan_kernel(
    const float* __restrict__ x,     // (3, NB, TT)
    const float* __restrict__ W_ih,  // (80, 3)
    const float* __restrict__ W_hh,  // (80, 20)
    const float* __restrict__ b_ih,  // (80,)
    const float* __restrict__ b_hh,  // (80,)
    float* __restrict__ hbuf)        // (NB, 20) out: h_last
{
    const int tid = threadIdx.x;
    const int lb  = tid / 80;          // local batch 0..3
    const int r   = tid - lb * 80;     // gate row 0..79
    const int gt  = r / 20;            // gate type
    const int b   = blockIdx.x * 4 + lb;

    __shared__ __align__(16) float hsh[4][HID];   // h state per local batch
    __shared__ float act[4][80];                  // activated gates

    // --- per-thread constants (held in registers) ---
    const float wih0 = W_ih[r * 3 + 0];
    const float wih1 = W_ih[r * 3 + 1];
    const float wih2 = W_ih[r * 3 + 2];
    float whh[HID];
#pragma unroll
    for (int k = 0; k < HID; ++k) whh[k] = W_hh[r * HID + k];
    const float bias = b_ih[r] + b_hh[r];

    // unified activation: a = scale * sigmoid(mult * acc) + off
    //   i,f,o: sigmoid(x)            -> mult=1, scale=1, off=0
    //   g:     tanh(x)=2*sig(2x)-1   -> mult=2, scale=2, off=-1
    const float mult  = (gt == 2) ? 2.0f : 1.0f;
    const float scale = (gt == 2) ? 2.0f : 1.0f;
    const float off   = (gt == 2) ? -1.0f : 0.0f;

    const float* xp0 = x + (size_t)0 * NB * TT + (size_t)b * TT;
    const float* xp1 = x + (size_t)1 * NB * TT + (size_t)b * TT;
    const float* xp2 = x + (size_t)2 * NB * TT + (size_t)b * TT;

    float c = 0.0f;       // cell state, live in threads r < HID (unit j = r)
    float hlast = 0.0f;
    if (r < HID) hsh[lb][r] = 0.0f;
    __syncthreads();

    // register prefetch pipeline, distance 2 (manual unroll-2 of t loop)
    float pa0 = xp0[0], pa1 = xp1[0], pa2 = xp2[0];
    float pb0 = xp0[1], pb1 = xp1[1], pb2 = xp2[1];

    auto step = [&](float x0, float x1, float x2) {
        // ---- phase 1: my gate's dot product ----
        const float4* h4 = (const float4*)(&hsh[lb][0]);
        float4 q0 = h4[0], q1 = h4[1], q2 = h4[2], q3 = h4[3], q4 = h4[4];
        // 4 accumulators to break the dependency chain (1.25 waves/SIMD only)
        float acc0 = fmaf(wih0, x0, bias);
        float acc1 = wih1 * x1;
        float acc2 = wih2 * x2;
        float acc3 = 0.0f;
        acc0 = fmaf(whh[0],  q0.x, acc0);
        acc1 = fmaf(whh[1],  q0.y, acc1);
        acc2 = fmaf(whh[2],  q0.z, acc2);
        acc3 = fmaf(whh[3],  q0.w, acc3);
        acc0 = fmaf(whh[4],  q1.x, acc0);
        acc1 = fmaf(whh[5],  q1.y, acc1);
        acc2 = fmaf(whh[6],  q1.z, acc2);
        acc3 = fmaf(whh[7],  q1.w, acc3);
        acc0 = fmaf(whh[8],  q2.x, acc0);
        acc1 = fmaf(whh[9],  q2.y, acc1);
        acc2 = fmaf(whh[10], q2.z, acc2);
        acc3 = fmaf(whh[11], q2.w, acc3);
        acc0 = fmaf(whh[12], q3.x, acc0);
        acc1 = fmaf(whh[13], q3.y, acc1);
        acc2 = fmaf(whh[14], q3.z, acc2);
        acc3 = fmaf(whh[15], q3.w, acc3);
        acc0 = fmaf(whh[16], q4.x, acc0);
        acc1 = fmaf(whh[17], q4.y, acc1);
        acc2 = fmaf(whh[18], q4.z, acc2);
        acc3 = fmaf(whh[19], q4.w, acc3);
        float acc = (acc0 + acc1) + (acc2 + acc3);

        // activation (fast exp + raw v_rcp; rel err ~1e-6, fine vs 4.6e-5 thr)
        float u = fast_rcp(1.0f + __expf(-mult * acc));
        float a = fmaf(scale, u, off);

        act[lb][r] = a;                 // coalesced, conflict-free
        __syncthreads();

        // ---- phase 2: c/h update, threads r < HID (unit j = r) ----
        if (r < HID) {
            float gi = act[lb][r];
            float gf = act[lb][HID + r];
            float gg = act[lb][2 * HID + r];
            float go = act[lb][3 * HID + r];
            c = fmaf(gf, c, gi * gg);
            float th = fmaf(2.0f, fast_rcp(1.0f + __expf(-2.0f * c)), -1.0f);
            hlast = go * th;
            hsh[lb][r] = hlast;
        }
        __syncthreads();
    };

    for (int t = 0; t < TT; t += 2) {
        float xa0 = pa0, xa1 = pa1, xa2 = pa2;
        int t2 = min(t + 2, TT - 1);
        pa0 = xp0[t2]; pa1 = xp1[t2]; pa2 = xp2[t2];
        step(xa0, xa1, xa2);

        float xb0 = pb0, xb1 = pb1, xb2 = pb2;
        int t3 = min(t + 3, TT - 1);
        pb0 = xp0[t3]; pb1 = xp1[t3]; pb2 = xp2[t3];
        step(xb0, xb1, xb2);
    }

    if (r < HID) hbuf[(size_t)b * HID + r] = hlast;
}

// ---------------------------------------------------------------------------
// Kernel 2: head — y = relu(h)@fc_w.T + fc_b ; z = [lastAction, y]·conv_w + cb
// logits = [1, z], softmax over 1025. Single block, thread = batch.
// ---------------------------------------------------------------------------
__global__ __launch_bounds__(1024) void head_kernel(
    const float* __restrict__ hbuf,       // (NB, 20)
    const float* __restrict__ lastAction, // (NB,)
    const float* __restrict__ fc_w,       // (20, 20)
    const float* __restrict__ fc_b,       // (20,)
    const float* __restrict__ conv_w,     // (21,)
    const float* __restrict__ conv_b,     // (1,)
    float* __restrict__ out)              // (NB+1,)
{
    const int b = threadIdx.x;
    __shared__ float red[1024];

    float hv[HID];
#pragma unroll
    for (int j = 0; j < HID; ++j) {
        float v = hbuf[(size_t)b * HID + j];
        hv[j] = v > 0.0f ? v : 0.0f;
    }

    float z = conv_b[0] + conv_w[0] * lastAction[b];
#pragma unroll
    for (int k = 0; k < HID; ++k) {
        float y = fc_b[k];
#pragma unroll
        for (int j = 0; j < HID; ++j) y = fmaf(hv[j], fc_w[k * HID + j], y);
        z = fmaf(conv_w[1 + k], y, z);
    }

    // max over logits {1.0, z_0..z_1023}
    red[b] = z;
    __syncthreads();
#pragma unroll
    for (int s = 512; s > 0; s >>= 1) {
        if (b < s) red[b] = fmaxf(red[b], red[b + s]);
        __syncthreads();
    }
    float m = fmaxf(red[0], 1.0f);
    __syncthreads();

    float e = __expf(z - m);
    red[b] = e;
    __syncthreads();
#pragma unroll
    for (int s = 512; s > 0; s >>= 1) {
        if (b < s) red[b] += red[b + s];
        __syncthreads();
    }
    float S = red[0] + __expf(1.0f - m);
    float inv = 1.0f / S;

    out[1 + b] = e * inv;
    if (b == 0) out[0] = __expf(1.0f - m) * inv;
}

// ---------------------------------------------------------------------------
extern "C" void kernel_launch(void* const* d_in, const int* in_sizes, int n_in,
                              void* d_out, int out_size, void* d_ws, size_t ws_size,
                              hipStream_t stream) {
    const float* x      = (const float*)d_in[0];
    const float* lastA  = (const float*)d_in[1];
    const float* W_ih   = (const float*)d_in[2];
    const float* W_hh   = (const float*)d_in[3];
    const float* b_ih   = (const float*)d_in[4];
    const float* b_hh   = (const float*)d_in[5];
    const float* fc_w   = (const float*)d_in[6];
    const float* fc_b   = (const float*)d_in[7];
    const float* conv_w = (const float*)d_in[8];
    const float* conv_b = (const float*)d_in[9];
    float* out  = (float*)d_out;
    float* hbuf = (float*)d_ws;   // NB*HID floats = 80 KB scratch

    lstm_scan_kernel<<<NB / 4, 320, 0, stream>>>(x, W_ih, W_hh, b_ih, b_hh, hbuf);
    head_kernel<<<1, 1024, 0, stream>>>(hbuf, lastA, fc_w, fc_b, conv_w, conv_b, out);
}

// Round 2
// 1388.022 us; speedup vs baseline: 1.2264x; 1.2264x over previous
//
#include <hip/hip_runtime.h>

#define FEAT 3
#define HID  20
#define NB   1024
#define TT   4096

__device__ __forceinline__ float fast_rcp(float x) { return __builtin_amdgcn_rcpf(x); }

// ---------------------------------------------------------------------------
// LSTM scan: 1 block = 1 wave (64 lanes) = 1 batch. Grid = 1024 = 4 waves/CU.
// Lane l = g*16 + u  (g in 0..3, u in 0..15) computes gate row r1 = g*20+u.
// Lanes 0..15 additionally compute the 16 leftover rows (units 16..19):
//   lane l<16: r2 = (l>>2)*20 + 16 + (l&3).
// c/h update for units 0..15 in lane u (gathers f,g,o via shfl_xor 16/32/48);
// for units 16..19 in lanes 0..3 (gathers via shfl_xor 4/8/12 on the r2 act).
// h (20 floats) broadcast via LDS; single-wave workgroup => barrier is cheap.
// ---------------------------------------------------------------------------
__global__ __launch_bounds__(64) void lstm_scan_kernel(
    const float* __restrict__ x,     // (3, NB, TT)
    const float* __restrict__ W_ih,  // (80, 3)
    const float* __restrict__ W_hh,  // (80, 20)
    const float* __restrict__ b_ih,  // (80,)
    const float* __restrict__ b_hh,  // (80,)
    float* __restrict__ hbuf)        // (NB, 20)
{
    const int lane = threadIdx.x;       // 0..63
    const int b    = blockIdx.x;        // batch
    const int g1   = lane >> 4;
    const int u1   = lane & 15;
    const int r1   = g1 * 20 + u1;
    const int g2   = (lane < 16) ? (lane >> 2) : g1;
    const int r2   = (lane < 16) ? (g2 * 20 + 16 + (lane & 3)) : r1;

    // pre-scale: acc = -m*(W.v + b) so gate = post_s * rcp(1+exp(acc)) + post_o
    //   sigmoid: m=1, post=(1,0);  tanh (g-gate, g==2): m=2, post=(2,-1)
    const float s1 = (g1 == 2) ? -2.0f : -1.0f;
    const float s2 = (g2 == 2) ? -2.0f : -1.0f;
    const float p1s = (g1 == 2) ? 2.0f : 1.0f, p1o = (g1 == 2) ? -1.0f : 0.0f;
    const float p2s = (g2 == 2) ? 2.0f : 1.0f, p2o = (g2 == 2) ? -1.0f : 0.0f;

    float w1[23], w2[23];
#pragma unroll
    for (int k = 0; k < 3; ++k)  w1[k]     = W_ih[r1 * 3 + k] * s1;
#pragma unroll
    for (int k = 0; k < 20; ++k) w1[3 + k] = W_hh[r1 * 20 + k] * s1;
#pragma unroll
    for (int k = 0; k < 3; ++k)  w2[k]     = W_ih[r2 * 3 + k] * s2;
#pragma unroll
    for (int k = 0; k < 20; ++k) w2[3 + k] = W_hh[r2 * 20 + k] * s2;
    const float bias1 = (b_ih[r1] + b_hh[r1]) * s1;
    const float bias2 = (b_ih[r2] + b_hh[r2]) * s2;

    __shared__ __align__(16) float hsh[32];   // h[0..19] for this batch

    const float* xb0 = x + (size_t)b * TT;
    const float* xb1 = x + (size_t)NB * TT + (size_t)b * TT;
    const float* xb2 = x + (size_t)2 * NB * TT + (size_t)b * TT;

    float h[HID];
#pragma unroll
    for (int k = 0; k < HID; ++k) h[k] = 0.0f;
    float c1 = 0.0f, c2 = 0.0f;
    float h1v = 0.0f, h2v = 0.0f;

    auto step = [&](float x0, float x1, float x2) {
        // row 1 dot (pre-scaled)
        float a0 = fmaf(w1[0], x0, bias1);
        float a1 = w1[1] * x1;
        float a2 = w1[2] * x2;
        float a3 = 0.0f;
        // row 2 dot
        float d0 = fmaf(w2[0], x0, bias2);
        float d1 = w2[1] * x1;
        float d2 = w2[2] * x2;
        float d3 = 0.0f;
#pragma unroll
        for (int k = 0; k < 20; k += 4) {
            a0 = fmaf(w1[3 + k], h[k],     a0);
            a1 = fmaf(w1[4 + k], h[k + 1], a1);
            a2 = fmaf(w1[5 + k], h[k + 2], a2);
            a3 = fmaf(w1[6 + k], h[k + 3], a3);
            d0 = fmaf(w2[3 + k], h[k],     d0);
            d1 = fmaf(w2[4 + k], h[k + 1], d1);
            d2 = fmaf(w2[5 + k], h[k + 2], d2);
            d3 = fmaf(w2[6 + k], h[k + 3], d3);
        }
        float z1 = (a0 + a1) + (a2 + a3);
        float z2 = (d0 + d1) + (d2 + d3);

        float act1 = fmaf(p1s, fast_rcp(1.0f + __expf(z1)), p1o);
        float act2 = fmaf(p2s, fast_rcp(1.0f + __expf(z2)), p2o);

        // gathers (valid where used; garbage elsewhere is harmless)
        float f1 = __shfl_xor(act1, 16);
        float g1v = __shfl_xor(act1, 32);
        float o1 = __shfl_xor(act1, 48);
        float f2 = __shfl_xor(act2, 4);
        float g2v = __shfl_xor(act2, 8);
        float o2 = __shfl_xor(act2, 12);

        // unit u (lanes 0..15): act1 = i-gate there
        c1 = fmaf(f1, c1, act1 * g1v);
        float th1 = fmaf(2.0f, fast_rcp(1.0f + __expf(-2.0f * c1)), -1.0f);
        h1v = o1 * th1;
        // unit 16+l (lanes 0..3): act2 = i-gate there
        c2 = fmaf(f2, c2, act2 * g2v);
        float th2 = fmaf(2.0f, fast_rcp(1.0f + __expf(-2.0f * c2)), -1.0f);
        h2v = o2 * th2;

        if (lane < 16) hsh[lane] = h1v;
        if (lane < 4)  hsh[16 + lane] = h2v;
        __syncthreads();   // single-wave workgroup: compiles to waitcnt (cheap)
        const float4* h4 = (const float4*)hsh;
        float4 q0 = h4[0], q1 = h4[1], q2 = h4[2], q3 = h4[3], q4 = h4[4];
        h[0] = q0.x;  h[1] = q0.y;  h[2] = q0.z;  h[3] = q0.w;
        h[4] = q1.x;  h[5] = q1.y;  h[6] = q1.z;  h[7] = q1.w;
        h[8] = q2.x;  h[9] = q2.y;  h[10] = q2.z; h[11] = q2.w;
        h[12] = q3.x; h[13] = q3.y; h[14] = q3.z; h[15] = q3.w;
        h[16] = q4.x; h[17] = q4.y; h[18] = q4.z; h[19] = q4.w;
    };

    // x prefetch: 3 streams, float4 per 4 steps, distance-1 iteration pipeline
    float4 cx0 = *(const float4*)(xb0);
    float4 cx1 = *(const float4*)(xb1);
    float4 cx2 = *(const float4*)(xb2);
    for (int t = 0; t < TT; t += 4) {
        const int tn = (t + 4 < TT) ? (t + 4) : t;
        float4 nx0 = *(const float4*)(xb0 + tn);
        float4 nx1 = *(const float4*)(xb1 + tn);
        float4 nx2 = *(const float4*)(xb2 + tn);
        step(cx0.x, cx1.x, cx2.x);
        step(cx0.y, cx1.y, cx2.y);
        step(cx0.z, cx1.z, cx2.z);
        step(cx0.w, cx1.w, cx2.w);
        cx0 = nx0; cx1 = nx1; cx2 = nx2;
    }

    if (lane < 16) hbuf[(size_t)b * HID + lane] = h1v;
    if (lane < 4)  hbuf[(size_t)b * HID + 16 + lane] = h2v;
}

// ---------------------------------------------------------------------------
// Head: y = relu(h)@fc_w.T + fc_b ; z = [lastAction, y]·conv_w + conv_b ;
// softmax over [1, z_0..z_1023]. One block, thread = batch.
// ---------------------------------------------------------------------------
__global__ __launch_bounds__(1024) void head_kernel(
    const float* __restrict__ hbuf,       // (NB, 20)
    const float* __restrict__ lastAction, // (NB,)
    const float* __restrict__ fc_w,       // (20, 20)
    const float* __restrict__ fc_b,       // (20,)
    const float* __restrict__ conv_w,     // (21,)
    const float* __restrict__ conv_b,     // (1,)
    float* __restrict__ out)              // (NB+1,)
{
    const int b = threadIdx.x;
    __shared__ float red[1024];

    float hv[HID];
#pragma unroll
    for (int j = 0; j < HID; ++j) {
        float v = hbuf[(size_t)b * HID + j];
        hv[j] = v > 0.0f ? v : 0.0f;
    }

    float z = conv_b[0] + conv_w[0] * lastAction[b];
#pragma unroll
    for (int k = 0; k < HID; ++k) {
        float y = fc_b[k];
#pragma unroll
        for (int j = 0; j < HID; ++j) y = fmaf(hv[j], fc_w[k * HID + j], y);
        z = fmaf(conv_w[1 + k], y, z);
    }

    red[b] = z;
    __syncthreads();
#pragma unroll
    for (int s = 512; s > 0; s >>= 1) {
        if (b < s) red[b] = fmaxf(red[b], red[b + s]);
        __syncthreads();
    }
    float m = fmaxf(red[0], 1.0f);
    __syncthreads();

    float e = __expf(z - m);
    red[b] = e;
    __syncthreads();
#pragma unroll
    for (int s = 512; s > 0; s >>= 1) {
        if (b < s) red[b] += red[b + s];
        __syncthreads();
    }
    float S = red[0] + __expf(1.0f - m);
    float inv = 1.0f / S;

    out[1 + b] = e * inv;
    if (b == 0) out[0] = __expf(1.0f - m) * inv;
}

// ---------------------------------------------------------------------------
extern "C" void kernel_launch(void* const* d_in, const int* in_sizes, int n_in,
                              void* d_out, int out_size, void* d_ws, size_t ws_size,
                              hipStream_t stream) {
    const float* x      = (const float*)d_in[0];
    const float* lastA  = (const float*)d_in[1];
    const float* W_ih   = (const float*)d_in[2];
    const float* W_hh   = (const float*)d_in[3];
    const float* b_ih   = (const float*)d_in[4];
    const float* b_hh   = (const float*)d_in[5];
    const float* fc_w   = (const float*)d_in[6];
    const float* fc_b   = (const float*)d_in[7];
    const float* conv_w = (const float*)d_in[8];
    const float* conv_b = (const float*)d_in[9];
    float* out  = (float*)d_out;
    float* hbuf = (float*)d_ws;   // NB*HID floats = 80 KB scratch

    lstm_scan_kernel<<<NB, 64, 0, stream>>>(x, W_ih, W_hh, b_ih, b_hh, hbuf);
    head_kernel<<<1, 1024, 0, stream>>>(hbuf, lastA, fc_w, fc_b, conv_w, conv_b, out);
}

// Round 3
// 882.121 us; speedup vs baseline: 1.9298x; 1.5735x over previous
//
#include <hip/hip_runtime.h>

#define FEAT 3
#define HID  20
#define NB   1024
#define TT   4096

__device__ __forceinline__ float fast_rcp(float x) { return __builtin_amdgcn_rcpf(x); }
__device__ __forceinline__ float fast_exp2(float x) { return __builtin_amdgcn_exp2f(x); }

// quad_perm broadcast of slot G (0..3) within each group of 4 lanes.
// dpp_ctrl = G * 0x55 (pattern [G,G,G,G]). Full-rate VALU, no DS pipe.
template <int CTRL>
__device__ __forceinline__ float dpp_bcast(float v) {
    return __int_as_float(__builtin_amdgcn_mov_dpp(__float_as_int(v), CTRL, 0xF, 0xF, true));
}

__device__ __forceinline__ float bcast_lane(float v, int lane) {
    return __int_as_float(__builtin_amdgcn_readlane(__float_as_int(v), lane));
}

// ---------------------------------------------------------------------------
// LSTM scan: 1 block = 1 wave = 1 batch; grid = 1024 = exactly 1 wave/SIMD.
// Lane l: row1 = g1*20+u1 with u1=l>>2 (0..15), g1=l&3  (gates quad-adjacent)
//         row2 = g2*20+u2 with u2=16+(l>>4),   g2=l&3  (units 16..19, 4x redundant)
// No DS ops anywhere in the loop: gate gathers via DPP quad_perm, h broadcast
// via v_readlane -> SGPR operands of the dot FMAs.
// Weights pre-scaled by -log2(e) (sigmoid rows) / -2*log2(e) (g-gate rows) so
// every activation is raw v_exp_f32; cell state kept in scaled domain
// c' = -2*log2e*c, recurrence c' = f*c' + i*(S*g), tanh(c) = 2*rcp(1+exp2(c'))-1.
// ---------------------------------------------------------------------------
__global__ __launch_bounds__(64) void lstm_scan_kernel(
    const float* __restrict__ x,     // (3, NB, TT)
    const float* __restrict__ W_ih,  // (80, 3)
    const float* __restrict__ W_hh,  // (80, 20)
    const float* __restrict__ b_ih,  // (80,)
    const float* __restrict__ b_hh,  // (80,)
    float* __restrict__ hbuf)        // (NB, 20)
{
    const int lane = threadIdx.x;
    const int b    = blockIdx.x;

    const int u1 = lane >> 2;          // 0..15
    const int g1 = lane & 3;
    const int r1 = g1 * 20 + u1;
    const int u2 = 16 + (lane >> 4);   // 16..19
    const int g2 = lane & 3;
    const int r2 = g2 * 20 + u2;

    const float LOG2E = 1.44269504088896340736f;
    const float S = -2.0f * LOG2E;     // scaled-g / scaled-c domain constant

    const float s1 = (g1 == 2) ? -2.0f * LOG2E : -LOG2E;
    const float s2 = (g2 == 2) ? -2.0f * LOG2E : -LOG2E;
    // act = fma(ps, rcp(1+exp2(z')), po):
    //   sigmoid rows: ps=1, po=0  -> sigma(z)
    //   g rows:       ps=2S, po=-S -> S*tanh(z)   (scaled for c' recurrence)
    const float ps1 = (g1 == 2) ? 2.0f * S : 1.0f;
    const float po1 = (g1 == 2) ? -S : 0.0f;
    const float ps2 = (g2 == 2) ? 2.0f * S : 1.0f;
    const float po2 = (g2 == 2) ? -S : 0.0f;

    float w1x[3], w2x[3], w1h[HID], w2h[HID];
#pragma unroll
    for (int k = 0; k < 3; ++k)  w1x[k] = W_ih[r1 * 3 + k] * s1;
#pragma unroll
    for (int k = 0; k < HID; ++k) w1h[k] = W_hh[r1 * HID + k] * s1;
#pragma unroll
    for (int k = 0; k < 3; ++k)  w2x[k] = W_ih[r2 * 3 + k] * s2;
#pragma unroll
    for (int k = 0; k < HID; ++k) w2h[k] = W_hh[r2 * HID + k] * s2;
    const float bias1 = (b_ih[r1] + b_hh[r1]) * s1;
    const float bias2 = (b_ih[r2] + b_hh[r2]) * s2;

    const float* xb0 = x + (size_t)b * TT;
    const float* xb1 = x + (size_t)NB * TT + (size_t)b * TT;
    const float* xb2 = x + (size_t)2 * NB * TT + (size_t)b * TT;

    float c1 = 0.0f, c2 = 0.0f;      // scaled cell state c'
    float h1v = 0.0f, h2v = 0.0f;    // h of unit u1 / u2 (redundant per quad)

    auto step = [&](float x0, float x1, float x2) {
        // ---- h broadcast: readlane -> wave-uniform (SGPR) values ----
        float hs[HID];
#pragma unroll
        for (int u = 0; u < 16; ++u) hs[u] = bcast_lane(h1v, 4 * u);
#pragma unroll
        for (int a = 0; a < 4; ++a) hs[16 + a] = bcast_lane(h2v, 16 * a);

        // ---- dot products (pre-scaled weights) ----
        float A0 = fmaf(w1x[0], x0, bias1);
        float A1 = w1x[1] * x1;
        float A2 = w1x[2] * x2;
        float A3 = w1h[0] * hs[0];
        float D0 = fmaf(w2x[0], x0, bias2);
        float D1 = w2x[1] * x1;
        float D2 = w2x[2] * x2;
        float D3 = w2h[0] * hs[0];
#pragma unroll
        for (int k = 1; k < HID; k += 4) {
            A0 = fmaf(w1h[k],     hs[k],     A0);
            A1 = fmaf(w1h[k + 1], hs[k + 1], A1);
            A2 = fmaf(w1h[k + 2], hs[k + 2], A2);
            if (k + 3 < HID) A3 = fmaf(w1h[k + 3], hs[k + 3], A3);
            D0 = fmaf(w2h[k],     hs[k],     D0);
            D1 = fmaf(w2h[k + 1], hs[k + 1], D1);
            D2 = fmaf(w2h[k + 2], hs[k + 2], D2);
            if (k + 3 < HID) D3 = fmaf(w2h[k + 3], hs[k + 3], D3);
        }
        float z1 = (A0 + A1) + (A2 + A3);
        float z2 = (D0 + D1) + (D2 + D3);

        // ---- activations: raw v_exp + v_rcp + fma ----
        float act1 = fmaf(ps1, fast_rcp(1.0f + fast_exp2(z1)), po1);
        float act2 = fmaf(ps2, fast_rcp(1.0f + fast_exp2(z2)), po2);

        // ---- gate gathers: DPP quad_perm broadcasts (no DS pipe) ----
        float vi1 = dpp_bcast<0x00>(act1);
        float vf1 = dpp_bcast<0x55>(act1);
        float vg1 = dpp_bcast<0xAA>(act1);
        float vo1 = dpp_bcast<0xFF>(act1);
        float vi2 = dpp_bcast<0x00>(act2);
        float vf2 = dpp_bcast<0x55>(act2);
        float vg2 = dpp_bcast<0xAA>(act2);
        float vo2 = dpp_bcast<0xFF>(act2);

        // ---- c/h update (scaled-c domain) ----
        c1 = fmaf(vf1, c1, vi1 * vg1);
        float th1 = fmaf(2.0f, fast_rcp(1.0f + fast_exp2(c1)), -1.0f);
        h1v = vo1 * th1;
        c2 = fmaf(vf2, c2, vi2 * vg2);
        float th2 = fmaf(2.0f, fast_rcp(1.0f + fast_exp2(c2)), -1.0f);
        h2v = vo2 * th2;
    };

    // x pipeline: float4 per 4 steps, 3 streams, 8-step prefetch distance.
    float4 a0 = *(const float4*)(xb0);
    float4 a1 = *(const float4*)(xb1);
    float4 a2 = *(const float4*)(xb2);
    float4 b0 = *(const float4*)(xb0 + 4);
    float4 b1 = *(const float4*)(xb1 + 4);
    float4 b2 = *(const float4*)(xb2 + 4);

    for (int t = 0; t < TT; t += 8) {
        const int tn = (t + 8 < TT) ? (t + 8) : t;
        float4 n0 = *(const float4*)(xb0 + tn);
        float4 n1 = *(const float4*)(xb1 + tn);
        float4 n2 = *(const float4*)(xb2 + tn);
        step(a0.x, a1.x, a2.x);
        step(a0.y, a1.y, a2.y);
        step(a0.z, a1.z, a2.z);
        step(a0.w, a1.w, a2.w);

        const int tm = (t + 12 < TT) ? (t + 12) : t;
        float4 m0 = *(const float4*)(xb0 + tm);
        float4 m1 = *(const float4*)(xb1 + tm);
        float4 m2 = *(const float4*)(xb2 + tm);
        step(b0.x, b1.x, b2.x);
        step(b0.y, b1.y, b2.y);
        step(b0.z, b1.z, b2.z);
        step(b0.w, b1.w, b2.w);

        a0 = n0; a1 = n1; a2 = n2;
        b0 = m0; b1 = m1; b2 = m2;
    }

    // h[u1] valid in all lanes of quad u1; h[u2] valid in all lanes of row.
    if ((lane & 3) == 0)  hbuf[(size_t)b * HID + (lane >> 2)] = h1v;
    if ((lane & 15) == 0) hbuf[(size_t)b * HID + 16 + (lane >> 4)] = h2v;
}

// ---------------------------------------------------------------------------
// Head: y = relu(h)@fc_w.T + fc_b ; z = [lastAction, y]·conv_w + conv_b ;
// softmax over [1, z_0..z_1023]. One block, thread = batch.
// ---------------------------------------------------------------------------
__global__ __launch_bounds__(1024) void head_kernel(
    const float* __restrict__ hbuf,       // (NB, 20)
    const float* __restrict__ lastAction, // (NB,)
    const float* __restrict__ fc_w,       // (20, 20)
    const float* __restrict__ fc_b,       // (20,)
    const float* __restrict__ conv_w,     // (21,)
    const float* __restrict__ conv_b,     // (1,)
    float* __restrict__ out)              // (NB+1,)
{
    const int b = threadIdx.x;
    __shared__ float red[1024];

    float hv[HID];
#pragma unroll
    for (int j = 0; j < HID; ++j) {
        float v = hbuf[(size_t)b * HID + j];
        hv[j] = v > 0.0f ? v : 0.0f;
    }

    float z = conv_b[0] + conv_w[0] * lastAction[b];
#pragma unroll
    for (int k = 0; k < HID; ++k) {
        float y = fc_b[k];
#pragma unroll
        for (int j = 0; j < HID; ++j) y = fmaf(hv[j], fc_w[k * HID + j], y);
        z = fmaf(conv_w[1 + k], y, z);
    }

    red[b] = z;
    __syncthreads();
#pragma unroll
    for (int s = 512; s > 0; s >>= 1) {
        if (b < s) red[b] = fmaxf(red[b], red[b + s]);
        __syncthreads();
    }
    float m = fmaxf(red[0], 1.0f);
    __syncthreads();

    float e = __expf(z - m);
    red[b] = e;
    __syncthreads();
#pragma unroll
    for (int s = 512; s > 0; s >>= 1) {
        if (b < s) red[b] += red[b + s];
        __syncthreads();
    }
    float S = red[0] + __expf(1.0f - m);
    float inv = 1.0f / S;

    out[1 + b] = e * inv;
    if (b == 0) out[0] = __expf(1.0f - m) * inv;
}

// ---------------------------------------------------------------------------
extern "C" void kernel_launch(void* const* d_in, const int* in_sizes, int n_in,
                              void* d_out, int out_size, void* d_ws, size_t ws_size,
                              hipStream_t stream) {
    const float* x      = (const float*)d_in[0];
    const float* lastA  = (const float*)d_in[1];
    const float* W_ih   = (const float*)d_in[2];
    const float* W_hh   = (const float*)d_in[3];
    const float* b_ih   = (const float*)d_in[4];
    const float* b_hh   = (const float*)d_in[5];
    const float* fc_w   = (const float*)d_in[6];
    const float* fc_b   = (const float*)d_in[7];
    const float* conv_w = (const float*)d_in[8];
    const float* conv_b = (const float*)d_in[9];
    float* out  = (float*)d_out;
    float* hbuf = (float*)d_ws;   // NB*HID floats = 80 KB scratch

    lstm_scan_kernel<<<NB, 64, 0, stream>>>(x, W_ih, W_hh, b_ih, b_hh, hbuf);
    head_kernel<<<1, 1024, 0, stream>>>(hbuf, lastA, fc_w, fc_b, conv_w, conv_b, out);
}